// Round 1
// baseline (569.328 us; speedup 1.0000x reference)
//
#include <hip/hip_runtime.h>

#define CDIV(a,b) (((a)+(b)-1)/(b))

// ---------------------------------------------------------------------------
// conv1: feats [N,4] x W1 [27,4,32] -> x1 [N,32]   (submanifold, s1[k][j] in {j,N})
// thread = (row j, channel d). 8 rows per 256-thread block.
// ---------------------------------------------------------------------------
__global__ __launch_bounds__(256) void conv1_k(
    const float* __restrict__ feats, const float* __restrict__ W1,
    const int* __restrict__ g1, const int* __restrict__ s1,
    float* __restrict__ x1, int N)
{
    __shared__ float w[27 * 4 * 32];   // 13.8 KB
    int tid = threadIdx.x;
    for (int i = tid; i < 27 * 4 * 32; i += 256) w[i] = W1[i];
    __syncthreads();

    int d = tid & 31;
    int j = blockIdx.x * 8 + (tid >> 5);
    if (j >= N) return;

    float acc = 0.f;
    for (int k = 0; k < 27; ++k) {
        int s = s1[(size_t)k * N + j];
        if (s != N) {                       // found: s == j
            int g = g1[(size_t)k * N + j];
            float4 f = *reinterpret_cast<const float4*>(feats + (size_t)g * 4);
            const float* wk = w + k * 128;
            acc += f.x * wk[d] + f.y * wk[32 + d] + f.z * wk[64 + d] + f.w * wk[96 + d];
        }
    }
    x1[(size_t)j * 32 + d] = acc;
}

// ---------------------------------------------------------------------------
// conv2: x1 [N,32] x W2 [27,32,32] -> x2 [M,32]   (strided, s2[k][j] in {j,M})
// 64-row tile per block. Gather found rows to LDS (misses -> zeros).
// Thread tile: 4 rows x 2 channels (d0, d0+16). 256 threads = 16 q x 16 d0.
// ---------------------------------------------------------------------------
__global__ __launch_bounds__(256) void conv2_k(
    const float* __restrict__ x1, const float* __restrict__ W2,
    const int* __restrict__ g2, const int* __restrict__ s2,
    float* __restrict__ x2, int M)
{
    __shared__ float fb[64 * 32];      // 8 KB gathered tile
    int tid = threadIdx.x;
    int jbase = blockIdx.x * 64;
    int d0 = tid & 15;
    int q  = tid >> 4;                 // 0..15 -> rows q*4 .. q*4+3

    float acc[4][2];
    #pragma unroll
    for (int r = 0; r < 4; ++r) { acc[r][0] = 0.f; acc[r][1] = 0.f; }

    for (int k = 0; k < 27; ++k) {
        __syncthreads();               // protect fb from previous iteration's readers
        // gather: 64 rows x 32 cols = 512 float4 slots, 2 per thread
        #pragma unroll
        for (int i = 0; i < 2; ++i) {
            int slot = tid + i * 256;  // 0..511
            int row = slot >> 3;       // 0..63
            int cg  = slot & 7;        // float4 group
            int j = jbase + row;
            float4 v = make_float4(0.f, 0.f, 0.f, 0.f);
            if (j < M && s2[(size_t)k * M + j] != M) {
                int g = g2[(size_t)k * M + j];
                v = *reinterpret_cast<const float4*>(x1 + (size_t)g * 32 + cg * 4);
            }
            *reinterpret_cast<float4*>(fb + row * 32 + cg * 4) = v;
        }
        __syncthreads();

        // W2[k] columns d0 and d0+16 into registers (L2-resident, coalesced over lanes)
        const float* wk = W2 + k * 1024;
        float wa[32], wb[32];
        #pragma unroll
        for (int c = 0; c < 32; ++c) {
            wa[c] = wk[c * 32 + d0];
            wb[c] = wk[c * 32 + d0 + 16];
        }

        #pragma unroll
        for (int r = 0; r < 4; ++r) {
            const float* fr = fb + (q * 4 + r) * 32;
            #pragma unroll
            for (int cg = 0; cg < 8; ++cg) {
                float4 f = *reinterpret_cast<const float4*>(fr + cg * 4);
                acc[r][0] += f.x * wa[cg*4] + f.y * wa[cg*4+1] + f.z * wa[cg*4+2] + f.w * wa[cg*4+3];
                acc[r][1] += f.x * wb[cg*4] + f.y * wb[cg*4+1] + f.z * wb[cg*4+2] + f.w * wb[cg*4+3];
            }
        }
    }

    #pragma unroll
    for (int r = 0; r < 4; ++r) {
        int j = jbase + q * 4 + r;
        if (j < M) {
            x2[(size_t)j * 32 + d0]      = acc[r][0];
            x2[(size_t)j * 32 + d0 + 16] = acc[r][1];
        }
    }
}

// ---------------------------------------------------------------------------
// conv3: x2 [M,32] x W3 [27,32,2] -> out [M,2]   (submanifold on coarse grid)
// thread per output row; both output channels accumulated.
// ---------------------------------------------------------------------------
__global__ __launch_bounds__(256) void conv3_k(
    const float* __restrict__ x2, const float* __restrict__ W3,
    const int* __restrict__ g3, const int* __restrict__ s3,
    float* __restrict__ out, int M)
{
    __shared__ float w[27 * 64];       // 6.9 KB, layout [k][c][d]
    int tid = threadIdx.x;
    for (int i = tid; i < 27 * 64; i += 256) w[i] = W3[i];
    __syncthreads();

    int j = blockIdx.x * 256 + tid;
    if (j >= M) return;

    float a0 = 0.f, a1 = 0.f;
    for (int k = 0; k < 27; ++k) {
        int s = s3[(size_t)k * M + j];
        if (s != M) {
            int g = g3[(size_t)k * M + j];
            const float* xr = x2 + (size_t)g * 32;
            const float* wk = w + k * 64;
            #pragma unroll
            for (int cg = 0; cg < 8; ++cg) {
                float4 f = *reinterpret_cast<const float4*>(xr + cg * 4);
                a0 += f.x * wk[(cg*4+0)*2]   + f.y * wk[(cg*4+1)*2]
                    + f.z * wk[(cg*4+2)*2]   + f.w * wk[(cg*4+3)*2];
                a1 += f.x * wk[(cg*4+0)*2+1] + f.y * wk[(cg*4+1)*2+1]
                    + f.z * wk[(cg*4+2)*2+1] + f.w * wk[(cg*4+3)*2+1];
            }
        }
    }
    float2 o; o.x = a0; o.y = a1;
    *reinterpret_cast<float2*>(out + (size_t)j * 2) = o;
}

// ---------------------------------------------------------------------------
extern "C" void kernel_launch(void* const* d_in, const int* in_sizes, int n_in,
                              void* d_out, int out_size, void* d_ws, size_t ws_size,
                              hipStream_t stream) {
    const float* feats = (const float*)d_in[0];
    const float* W1    = (const float*)d_in[1];
    const float* W2    = (const float*)d_in[2];
    const float* W3    = (const float*)d_in[3];
    const int*   g1    = (const int*)d_in[4];
    const int*   s1    = (const int*)d_in[5];
    const int*   g2    = (const int*)d_in[6];
    const int*   s2    = (const int*)d_in[7];
    const int*   g3    = (const int*)d_in[8];
    const int*   s3    = (const int*)d_in[9];

    int N = in_sizes[0] / 4;    // 200000
    int M = in_sizes[6] / 27;   // stride-2 output count

    float* x1 = (float*)d_ws;                    // [N,32]
    float* x2 = x1 + (size_t)N * 32;             // [M,32]
    float* out = (float*)d_out;                  // [M,2]

    conv1_k<<<CDIV(N, 8),   256, 0, stream>>>(feats, W1, g1, s1, x1, N);
    conv2_k<<<CDIV(M, 64),  256, 0, stream>>>(x1, W2, g2, s2, x2, M);
    conv3_k<<<CDIV(M, 256), 256, 0, stream>>>(x2, W3, g3, s3, out, M);
}

// Round 3
// 550.932 us; speedup vs baseline: 1.0334x; 1.0334x over previous
//
#include <hip/hip_runtime.h>

#define CDIV(a,b) (((a)+(b)-1)/(b))

// ---------------------------------------------------------------------------
// W2 transpose: [27][32c][32d] -> [27][32d][32c]  (tiny, ~28k elems)
// ---------------------------------------------------------------------------
__global__ __launch_bounds__(256) void w2t_k(const float* __restrict__ W2,
                                             float* __restrict__ w2t) {
    int i = blockIdx.x * 256 + threadIdx.x;
    if (i < 27 * 1024) {
        int k = i >> 10, cd = i & 1023, c = cd >> 5, d = cd & 31;
        w2t[k * 1024 + d * 32 + c] = W2[i];
    }
}

// ---------------------------------------------------------------------------
// conv1: feats [N,4] x W1 [27,4,32] -> x1 [N,32]
// thread = (row j, channel d), 8 rows/block. Branchless, 9-k prefetch chunks.
// ---------------------------------------------------------------------------
__global__ __launch_bounds__(256) void conv1_k(
    const float* __restrict__ feats, const float* __restrict__ W1,
    const int* __restrict__ g1, const int* __restrict__ s1,
    float* __restrict__ x1, int N)
{
    __shared__ float w[27 * 128];
    int tid = threadIdx.x;
    for (int i = tid; i < 27 * 128; i += 256) w[i] = W1[i];
    __syncthreads();

    int d = tid & 31;
    int j = blockIdx.x * 8 + (tid >> 5);
    if (j >= N) return;

    float acc = 0.f;
    #pragma unroll
    for (int kc = 0; kc < 27; kc += 9) {
        int sv[9], gv[9];
        #pragma unroll
        for (int i = 0; i < 9; ++i) {
            sv[i] = s1[(size_t)(kc + i) * N + j];
            gv[i] = g1[(size_t)(kc + i) * N + j];
        }
        float4 f[9];
        #pragma unroll
        for (int i = 0; i < 9; ++i)
            f[i] = *reinterpret_cast<const float4*>(feats + (size_t)gv[i] * 4);
        #pragma unroll
        for (int i = 0; i < 9; ++i) {
            float m = (sv[i] != N) ? 1.f : 0.f;
            const float* wk = w + (kc + i) * 128;
            acc += m * (f[i].x * wk[d] + f[i].y * wk[32 + d]
                      + f[i].z * wk[64 + d] + f[i].w * wk[96 + d]);
        }
    }
    x1[(size_t)j * 32 + d] = acc;
}

// ---------------------------------------------------------------------------
// conv2: x1 [N,32] x W2t [27,32d,32c] -> x2 [M,32]
// 64-row tile, double-buffered LDS (stride 36), register prefetch of next k.
// Thread tile: 4 rows x 2 channels (d0, d0+16).
// ---------------------------------------------------------------------------
#define FBS 36   // padded row stride (2-way bank alias = free)
__global__ __launch_bounds__(256) void conv2_k(
    const float* __restrict__ x1, const float* __restrict__ w2t,
    const int* __restrict__ g2, const int* __restrict__ s2,
    float* __restrict__ x2, int M)
{
    __shared__ float fb[2][64 * FBS];
    int tid = threadIdx.x;
    int jbase = blockIdx.x * 64;
    int d0 = tid & 15;
    int q  = tid >> 4;

    // gather slots: this thread fills (row0,cg) and (row0+32,cg)
    int row0 = tid >> 3;
    int cg0  = tid & 7;
    int j0 = jbase + row0;
    int j1 = j0 + 32;
    int jc0 = j0 < M ? j0 : M - 1;   // clamped for safe index-array reads
    int jc1 = j1 < M ? j1 : M - 1;

    // prologue: gather k=0
    {
        int h0 = (j0 < M) && (s2[jc0] != M);
        int h1 = (j1 < M) && (s2[jc1] != M);
        int gg0 = g2[jc0], gg1 = g2[jc1];
        float4 v0 = *reinterpret_cast<const float4*>(x1 + (size_t)gg0 * 32 + cg0 * 4);
        float4 v1 = *reinterpret_cast<const float4*>(x1 + (size_t)gg1 * 32 + cg0 * 4);
        float m0 = h0 ? 1.f : 0.f, m1 = h1 ? 1.f : 0.f;
        v0.x *= m0; v0.y *= m0; v0.z *= m0; v0.w *= m0;
        v1.x *= m1; v1.y *= m1; v1.z *= m1; v1.w *= m1;
        *reinterpret_cast<float4*>(&fb[0][row0 * FBS + cg0 * 4]) = v0;
        *reinterpret_cast<float4*>(&fb[0][(row0 + 32) * FBS + cg0 * 4]) = v1;
    }
    __syncthreads();

    float acc[4][2];
    #pragma unroll
    for (int r = 0; r < 4; ++r) { acc[r][0] = 0.f; acc[r][1] = 0.f; }

    for (int k = 0; k < 27; ++k) {
        int cur = k & 1;

        // --- prefetch k+1 into registers (issued before compute) ---
        float4 p0 = make_float4(0.f, 0.f, 0.f, 0.f), p1 = p0;
        if (k + 1 < 27) {
            const int* sk = s2 + (size_t)(k + 1) * M;
            const int* gk = g2 + (size_t)(k + 1) * M;
            int h0 = (j0 < M) && (sk[jc0] != M);
            int h1 = (j1 < M) && (sk[jc1] != M);
            int gg0 = gk[jc0], gg1 = gk[jc1];
            p0 = *reinterpret_cast<const float4*>(x1 + (size_t)gg0 * 32 + cg0 * 4);
            p1 = *reinterpret_cast<const float4*>(x1 + (size_t)gg1 * 32 + cg0 * 4);
            float m0 = h0 ? 1.f : 0.f, m1 = h1 ? 1.f : 0.f;
            p0.x *= m0; p0.y *= m0; p0.z *= m0; p0.w *= m0;
            p1.x *= m1; p1.y *= m1; p1.z *= m1; p1.w *= m1;
        }

        // --- W columns for this k (transposed layout: 16 float4 loads) ---
        const float* wt = w2t + (size_t)k * 1024;
        float4 wa[8], wb[8];
        #pragma unroll
        for (int c4 = 0; c4 < 8; ++c4) {
            wa[c4] = *reinterpret_cast<const float4*>(wt + d0 * 32 + c4 * 4);
            wb[c4] = *reinterpret_cast<const float4*>(wt + (d0 + 16) * 32 + c4 * 4);
        }

        // --- compute from fb[cur] ---
        #pragma unroll
        for (int r = 0; r < 4; ++r) {
            const float* fr = &fb[cur][(q * 4 + r) * FBS];
            #pragma unroll
            for (int cg = 0; cg < 8; ++cg) {
                float4 f = *reinterpret_cast<const float4*>(fr + cg * 4);
                acc[r][0] += f.x * wa[cg].x + f.y * wa[cg].y + f.z * wa[cg].z + f.w * wa[cg].w;
                acc[r][1] += f.x * wb[cg].x + f.y * wb[cg].y + f.z * wb[cg].z + f.w * wb[cg].w;
            }
        }

        // --- write prefetched tile to other buffer ---
        if (k + 1 < 27) {
            *reinterpret_cast<float4*>(&fb[cur ^ 1][row0 * FBS + cg0 * 4]) = p0;
            *reinterpret_cast<float4*>(&fb[cur ^ 1][(row0 + 32) * FBS + cg0 * 4]) = p1;
        }
        __syncthreads();
    }

    #pragma unroll
    for (int r = 0; r < 4; ++r) {
        int j = jbase + q * 4 + r;
        if (j < M) {
            x2[(size_t)j * 32 + d0]      = acc[r][0];
            x2[(size_t)j * 32 + d0 + 16] = acc[r][1];
        }
    }
}

// ---------------------------------------------------------------------------
// conv3: x2 [M,32] x W3 [27,32,2] -> out [M,2]
// thread per row; all 27 s/g prefetched; branchless masked-dense (hit ~84%).
// ---------------------------------------------------------------------------
__global__ __launch_bounds__(256) void conv3_k(
    const float* __restrict__ x2, const float* __restrict__ W3,
    const int* __restrict__ g3, const int* __restrict__ s3,
    float* __restrict__ out, int M)
{
    __shared__ float w[27 * 64];
    int tid = threadIdx.x;
    for (int i = tid; i < 27 * 64; i += 256) w[i] = W3[i];
    __syncthreads();

    int j = blockIdx.x * 256 + tid;
    if (j >= M) return;

    int sv[27], gv[27];
    #pragma unroll
    for (int k = 0; k < 27; ++k) {
        sv[k] = s3[(size_t)k * M + j];
        gv[k] = g3[(size_t)k * M + j];
    }

    float a0 = 0.f, a1 = 0.f;
    #pragma unroll 3
    for (int k = 0; k < 27; ++k) {
        float m = (sv[k] != M) ? 1.f : 0.f;
        const float* xr = x2 + (size_t)gv[k] * 32;
        const float* wk = w + k * 64;
        #pragma unroll
        for (int cg = 0; cg < 8; ++cg) {
            float4 f  = *reinterpret_cast<const float4*>(xr + cg * 4);
            float4 wA = *reinterpret_cast<const float4*>(wk + cg * 8);      // c0d0 c0d1 c1d0 c1d1
            float4 wB = *reinterpret_cast<const float4*>(wk + cg * 8 + 4);  // c2d0 c2d1 c3d0 c3d1
            a0 += m * (f.x * wA.x + f.y * wA.z + f.z * wB.x + f.w * wB.z);
            a1 += m * (f.x * wA.y + f.y * wA.w + f.z * wB.y + f.w * wB.w);
        }
    }
    *reinterpret_cast<float2*>(out + (size_t)j * 2) = make_float2(a0, a1);
}

// ---------------------------------------------------------------------------
extern "C" void kernel_launch(void* const* d_in, const int* in_sizes, int n_in,
                              void* d_out, int out_size, void* d_ws, size_t ws_size,
                              hipStream_t stream) {
    const float* feats = (const float*)d_in[0];
    const float* W1    = (const float*)d_in[1];
    const float* W2    = (const float*)d_in[2];
    const float* W3    = (const float*)d_in[3];
    const int*   g1    = (const int*)d_in[4];
    const int*   s1    = (const int*)d_in[5];
    const int*   g2    = (const int*)d_in[6];
    const int*   s2    = (const int*)d_in[7];
    const int*   g3    = (const int*)d_in[8];
    const int*   s3    = (const int*)d_in[9];

    int N = in_sizes[0] / 4;    // 200000
    int M = in_sizes[6] / 27;   // stride-2 output count

    float* x1  = (float*)d_ws;                   // [N,32]
    float* x2  = x1 + (size_t)N * 32;            // [M,32]
    float* w2t = x2 + (size_t)M * 32;            // [27,32,32] transposed
    float* out = (float*)d_out;                  // [M,2]

    w2t_k <<<CDIV(27 * 1024, 256), 256, 0, stream>>>(W2, w2t);
    conv1_k<<<CDIV(N, 8),          256, 0, stream>>>(feats, W1, g1, s1, x1, N);
    conv2_k<<<CDIV(M, 64),         256, 0, stream>>>(x1, w2t, g2, s2, x2, M);
    conv3_k<<<CDIV(M, 256),        256, 0, stream>>>(x2, W3, g3, s3, out, M);
}

// Round 4
// 171.006 us; speedup vs baseline: 3.3293x; 3.2217x over previous
//
#include <hip/hip_runtime.h>

#define CDIV(a,b) (((a)+(b)-1)/(b))

typedef __attribute__((ext_vector_type(8))) short short8v;
typedef __attribute__((ext_vector_type(4))) short short4v;
typedef __attribute__((ext_vector_type(4))) float f32x4;

__device__ inline unsigned short f2bf(float x) {
    unsigned u = __builtin_bit_cast(unsigned, x);
    u += 0x7fffu + ((u >> 16) & 1u);          // round-to-nearest-even
    return (unsigned short)(u >> 16);
}

// ---------------------------------------------------------------------------
// prep_feats: feats f32 [N,4] -> featsh bf16 [N+1][4]; zero featsh[N], x1h[N]
// ---------------------------------------------------------------------------
__global__ __launch_bounds__(256) void prep_feats_k(
    const float* __restrict__ feats, unsigned short* __restrict__ featsh,
    unsigned short* __restrict__ x1h, int N)
{
    int i = blockIdx.x * 256 + threadIdx.x;
    if (i < N) {
        float4 f = *reinterpret_cast<const float4*>(feats + (size_t)i * 4);
        ushort4 h; h.x = f2bf(f.x); h.y = f2bf(f.y); h.z = f2bf(f.z); h.w = f2bf(f.w);
        *reinterpret_cast<ushort4*>(featsh + (size_t)i * 4) = h;
    } else if (i == N) {
        *reinterpret_cast<ushort4*>(featsh + (size_t)N * 4) = make_ushort4(0, 0, 0, 0);
        #pragma unroll
        for (int t = 0; t < 8; ++t)
            *reinterpret_cast<ushort4*>(x1h + (size_t)N * 32 + t * 4) = make_ushort4(0, 0, 0, 0);
    }
}

// ---------------------------------------------------------------------------
// prep_w: w2h[k][d][c] = bf16(W2[k][c][d])  (B^T layout for MFMA B-frag)
//         w1f[mf][n][kc] = bf16(W1[slot][c][n]), slot = mf*8 + kc/4, c = kc%3..
//         (k-folded B operand for conv1; slots 27..31 zero-padded)
// ---------------------------------------------------------------------------
__global__ __launch_bounds__(256) void prep_w_k(
    const float* __restrict__ W1, const float* __restrict__ W2,
    unsigned short* __restrict__ w2h, unsigned short* __restrict__ w1f)
{
    int i = blockIdx.x * 256 + threadIdx.x;
    if (i < 27 * 1024) {
        int k = i >> 10, c = (i >> 5) & 31, d = i & 31;
        w2h[k * 1024 + d * 32 + c] = f2bf(W2[i]);
    } else if (i < 27 * 1024 + 4096) {
        int idx = i - 27 * 1024;
        int mf = idx >> 10, n = (idx >> 5) & 31, kc = idx & 31;
        int slot = mf * 8 + (kc >> 2), c = kc & 3;
        float v = (slot < 27) ? W1[slot * 128 + c * 32 + n] : 0.f;
        w1f[mf * 1024 + n * 32 + kc] = f2bf(v);
    }
}

// ---------------------------------------------------------------------------
// conv1: featsh [N+1,4] x w1f -> x1h [N+1,32] bf16. Per-wave MFMA, k-folded:
// 4 mfma_16x16x32 pairs cover 32 k-slots x 4 channels. 16 rows/wave, no LDS.
// ---------------------------------------------------------------------------
__global__ __launch_bounds__(256, 6) void conv1_k(
    const unsigned short* __restrict__ featsh, const unsigned short* __restrict__ w1f,
    const int* __restrict__ g1, const int* __restrict__ s1,
    unsigned short* __restrict__ x1h, int N)
{
    int tid = threadIdx.x;
    int l = tid & 63, wv = tid >> 6;
    int lr = l & 15, kq = l >> 4;
    int rbase = blockIdx.x * 64 + wv * 16;
    int j = rbase + lr;
    int jc = j < N ? j : N - 1;

    // gather indices for this lane's 8 k-slots (miss / pad-slot -> zero row N)
    int gm[4][2];
    #pragma unroll
    for (int mf = 0; mf < 4; ++mf)
        #pragma unroll
        for (int t = 0; t < 2; ++t) {
            int slot = mf * 8 + kq * 2 + t;
            int v = N;
            if (slot < 27 && j < N) {
                int s = s1[(size_t)slot * N + jc];
                int g = g1[(size_t)slot * N + jc];
                v = (s != N) ? g : N;
            }
            gm[mf][t] = v;
        }

    f32x4 acc0 = {0.f, 0.f, 0.f, 0.f}, acc1 = {0.f, 0.f, 0.f, 0.f};
    const char* fb = (const char*)featsh;
    const char* wb = (const char*)w1f;
    #pragma unroll
    for (int mf = 0; mf < 4; ++mf) {
        short4v lo = *(const short4v*)(fb + (size_t)gm[mf][0] * 8);
        short4v hi = *(const short4v*)(fb + (size_t)gm[mf][1] * 8);
        short8v a = __builtin_shufflevector(lo, hi, 0, 1, 2, 3, 4, 5, 6, 7);
        short8v b0 = *(const short8v*)(wb + mf * 2048 + lr * 64 + kq * 16);
        short8v b1 = *(const short8v*)(wb + mf * 2048 + 1024 + lr * 64 + kq * 16);
        acc0 = __builtin_amdgcn_mfma_f32_16x16x32_bf16(a, b0, acc0, 0, 0, 0);
        acc1 = __builtin_amdgcn_mfma_f32_16x16x32_bf16(a, b1, acc1, 0, 0, 0);
    }
    // C/D: col = lane&15, row = (lane>>4)*4 + i
    #pragma unroll
    for (int i = 0; i < 4; ++i) {
        int j2 = rbase + kq * 4 + i;
        if (j2 < N) {
            x1h[(size_t)j2 * 32 + lr]      = f2bf(acc0[i]);
            x1h[(size_t)j2 * 32 + lr + 16] = f2bf(acc1[i]);
        }
    }
}

// ---------------------------------------------------------------------------
// conv2: x1h [N+1,32] bf16 x w2h -> x2 [M,32] f32. Per-wave MFMA GEMM:
// 16 rows/wave, A-frag gathered per-lane from global, B from L2. No LDS/sync.
// ---------------------------------------------------------------------------
__global__ __launch_bounds__(256, 6) void conv2_k(
    const unsigned short* __restrict__ x1h, const unsigned short* __restrict__ w2h,
    const int* __restrict__ g2, const int* __restrict__ s2,
    float* __restrict__ x2, int M, int N)
{
    int tid = threadIdx.x;
    int l = tid & 63, wv = tid >> 6;
    int lr = l & 15, kq = l >> 4;
    int rbase = blockIdx.x * 64 + wv * 16;
    int j = rbase + lr;
    int jc = j < M ? j : M - 1;

    int gm[27];
    #pragma unroll
    for (int k = 0; k < 27; ++k) {
        int s = s2[(size_t)k * M + jc];
        int g = g2[(size_t)k * M + jc];
        gm[k] = (s != M) ? g : N;          // row N of x1h is zeros
    }

    f32x4 acc0 = {0.f, 0.f, 0.f, 0.f}, acc1 = {0.f, 0.f, 0.f, 0.f};
    const char* xb = (const char*)x1h;
    const char* wb = (const char*)w2h;
    #pragma unroll
    for (int k = 0; k < 27; ++k) {
        short8v a  = *(const short8v*)(xb + (size_t)gm[k] * 64 + kq * 16);
        short8v b0 = *(const short8v*)(wb + k * 2048 + lr * 64 + kq * 16);
        short8v b1 = *(const short8v*)(wb + k * 2048 + 1024 + lr * 64 + kq * 16);
        acc0 = __builtin_amdgcn_mfma_f32_16x16x32_bf16(a, b0, acc0, 0, 0, 0);
        acc1 = __builtin_amdgcn_mfma_f32_16x16x32_bf16(a, b1, acc1, 0, 0, 0);
    }
    #pragma unroll
    for (int i = 0; i < 4; ++i) {
        int j2 = rbase + kq * 4 + i;
        if (j2 < M) {
            x2[(size_t)j2 * 32 + lr]      = acc0[i];
            x2[(size_t)j2 * 32 + lr + 16] = acc1[i];
        }
    }
}

// ---------------------------------------------------------------------------
// conv3: x2 [M,32] f32 x W3 [27,32,2] -> out [M,2]. 4 threads/row (8 ch each),
// hoisted masked indices, shfl_xor reduce. W3 in LDS.
// ---------------------------------------------------------------------------
__global__ __launch_bounds__(256, 6) void conv3_k(
    const float* __restrict__ x2, const float* __restrict__ W3,
    const int* __restrict__ g3, const int* __restrict__ s3,
    float* __restrict__ out, int M)
{
    __shared__ float w[27 * 64];
    int tid = threadIdx.x;
    for (int i = tid; i < 27 * 64; i += 256) w[i] = W3[i];
    __syncthreads();

    int q = tid & 3;
    int j = blockIdx.x * 64 + (tid >> 2);
    int jc = j < M ? j : M - 1;

    int gm[27];
    #pragma unroll
    for (int k = 0; k < 27; ++k) {
        int s = s3[(size_t)k * M + jc];
        int g = g3[(size_t)k * M + jc];
        gm[k] = (s != M) ? g : -1;
    }

    float a0 = 0.f, a1 = 0.f;
    #pragma unroll
    for (int k = 0; k < 27; ++k) {
        float m = gm[k] >= 0 ? 1.f : 0.f;
        int g = gm[k] >= 0 ? gm[k] : 0;
        const float* xr = x2 + (size_t)g * 32 + q * 8;
        float4 f0 = *(const float4*)(xr);
        float4 f1 = *(const float4*)(xr + 4);
        const float* wk = w + k * 64 + q * 16;   // [c][d] pairs for c=q*8..+8
        float4 wA = *(const float4*)(wk);
        float4 wB = *(const float4*)(wk + 4);
        float4 wC = *(const float4*)(wk + 8);
        float4 wD = *(const float4*)(wk + 12);
        a0 += m * (f0.x * wA.x + f0.y * wA.z + f0.z * wB.x + f0.w * wB.z
                 + f1.x * wC.x + f1.y * wC.z + f1.z * wD.x + f1.w * wD.z);
        a1 += m * (f0.x * wA.y + f0.y * wA.w + f0.z * wB.y + f0.w * wB.w
                 + f1.x * wC.y + f1.y * wC.w + f1.z * wD.y + f1.w * wD.w);
    }
    a0 += __shfl_xor(a0, 1); a0 += __shfl_xor(a0, 2);
    a1 += __shfl_xor(a1, 1); a1 += __shfl_xor(a1, 2);
    if (q == 0 && j < M)
        *reinterpret_cast<float2*>(out + (size_t)j * 2) = make_float2(a0, a1);
}

// ---------------------------------------------------------------------------
extern "C" void kernel_launch(void* const* d_in, const int* in_sizes, int n_in,
                              void* d_out, int out_size, void* d_ws, size_t ws_size,
                              hipStream_t stream) {
    const float* feats = (const float*)d_in[0];
    const float* W1    = (const float*)d_in[1];
    const float* W2    = (const float*)d_in[2];
    const float* W3    = (const float*)d_in[3];
    const int*   g1    = (const int*)d_in[4];
    const int*   s1    = (const int*)d_in[5];
    const int*   g2    = (const int*)d_in[6];
    const int*   s2    = (const int*)d_in[7];
    const int*   g3    = (const int*)d_in[8];
    const int*   s3    = (const int*)d_in[9];

    int N = in_sizes[0] / 4;    // 200000
    int M = in_sizes[6] / 27;   // stride-2 output count

    char* wsb = (char*)d_ws;
    size_t off = 0;
    auto alloc = [&](size_t bytes) {
        char* p = wsb + off;
        off = (off + bytes + 255) & ~(size_t)255;
        return p;
    };
    unsigned short* x1h    = (unsigned short*)alloc((size_t)(N + 1) * 64); // [N+1,32] bf16
    unsigned short* featsh = (unsigned short*)alloc((size_t)(N + 1) * 8);  // [N+1,4]  bf16
    unsigned short* w2h    = (unsigned short*)alloc(27 * 1024 * 2);        // [27,32,32] bf16 (B^T)
    unsigned short* w1f    = (unsigned short*)alloc(4 * 1024 * 2);         // [4,32,32]  bf16 (folded)
    float*          x2     = (float*)alloc((size_t)M * 128);               // [M,32] f32
    float* out = (float*)d_out;

    prep_feats_k<<<CDIV(N + 1, 256), 256, 0, stream>>>(feats, featsh, x1h, N);
    prep_w_k<<<CDIV(27 * 1024 + 4096, 256), 256, 0, stream>>>(W1, W2, w2h, w1f);
    conv1_k<<<CDIV(N, 64), 256, 0, stream>>>(featsh, w1f, g1, s1, x1h, N);
    conv2_k<<<CDIV(M, 64), 256, 0, stream>>>(x1h, w2h, g2, s2, x2, M, N);
    conv3_k<<<CDIV(M, 64), 256, 0, stream>>>(x2, W3, g3, s3, out, M);
}

// Round 5
// 168.285 us; speedup vs baseline: 3.3831x; 1.0162x over previous
//
#include <hip/hip_runtime.h>

#define CDIV(a,b) (((a)+(b)-1)/(b))

typedef __attribute__((ext_vector_type(8)))  short short8v;
typedef __attribute__((ext_vector_type(4)))  short short4v;
typedef __attribute__((ext_vector_type(16))) float f32x16;

__device__ inline unsigned short f2bf(float x) {
    unsigned u = __builtin_bit_cast(unsigned, x);
    u += 0x7fffu + ((u >> 16) & 1u);          // round-to-nearest-even
    return (unsigned short)(u >> 16);
}

// ---------------------------------------------------------------------------
// prep_feats: feats f32 [N,4] -> featsh bf16 [N+1][4]; zero featsh[N], x1h[N]
// ---------------------------------------------------------------------------
__global__ __launch_bounds__(256) void prep_feats_k(
    const float* __restrict__ feats, unsigned short* __restrict__ featsh,
    unsigned short* __restrict__ x1h, int N)
{
    int i = blockIdx.x * 256 + threadIdx.x;
    if (i < N) {
        float4 f = *reinterpret_cast<const float4*>(feats + (size_t)i * 4);
        ushort4 h; h.x = f2bf(f.x); h.y = f2bf(f.y); h.z = f2bf(f.z); h.w = f2bf(f.w);
        *reinterpret_cast<ushort4*>(featsh + (size_t)i * 4) = h;
    } else if (i == N) {
        *reinterpret_cast<ushort4*>(featsh + (size_t)N * 4) = make_ushort4(0, 0, 0, 0);
        #pragma unroll
        for (int t = 0; t < 8; ++t)
            *reinterpret_cast<ushort4*>(x1h + (size_t)N * 32 + t * 4) = make_ushort4(0, 0, 0, 0);
    }
}

// ---------------------------------------------------------------------------
// prep_w: w2h[k][d][c] = bf16(W2[k][c][d])           (B^T for MFMA B-frag)
//         w1f[m][n][kk] = bf16(W1[4m + kk/4][kk%4][n]), m=0..7, kk=0..15
//         (k-folded conv1 B operand for 32x32x16; slots 27..31 -> 0)
// ---------------------------------------------------------------------------
__global__ __launch_bounds__(256) void prep_w_k(
    const float* __restrict__ W1, const float* __restrict__ W2,
    unsigned short* __restrict__ w2h, unsigned short* __restrict__ w1f)
{
    int i = blockIdx.x * 256 + threadIdx.x;
    if (i < 27 * 1024) {
        int k = i >> 10, c = (i >> 5) & 31, d = i & 31;
        w2h[k * 1024 + d * 32 + c] = f2bf(W2[i]);
    } else if (i < 27 * 1024 + 4096) {
        int idx = i - 27 * 1024;
        int m = idx >> 9, n = (idx >> 4) & 31, kk = idx & 15;
        int slot = 4 * m + (kk >> 2), c = kk & 3;
        float v = (slot < 27) ? W1[slot * 128 + c * 32 + n] : 0.f;
        w1f[m * 512 + n * 16 + kk] = f2bf(v);
    }
}

// ---------------------------------------------------------------------------
// conv1: featsh [N+1,4] x w1f -> x1h [N+1,32] bf16.
// 32x32x16 MFMA, k-folded: 8 MFMAs cover 32 slots x 4 ch for 32 rows/wave.
// ---------------------------------------------------------------------------
__global__ __launch_bounds__(256) void conv1_k(
    const unsigned short* __restrict__ featsh, const unsigned short* __restrict__ w1f,
    const int* __restrict__ g1, const int* __restrict__ s1,
    unsigned short* __restrict__ x1h, int N)
{
    int tid = threadIdx.x;
    int l = tid & 63, wv = tid >> 6;
    int r = l & 31, h = l >> 5;
    int rbase = blockIdx.x * 128 + wv * 32;
    int j = rbase + r;
    int jc = j < N ? j : N - 1;

    // this lane's 16 slots: 4m + 2h + {0,1}, m=0..7  (miss/pad -> zero row N)
    int gm[8][2];
    #pragma unroll
    for (int m = 0; m < 8; ++m)
        #pragma unroll
        for (int t = 0; t < 2; ++t) {
            int slot = 4 * m + 2 * h + t;
            int v = N;
            if (slot < 27 && j < N) {
                int s = s1[(size_t)slot * N + jc];
                int g = g1[(size_t)slot * N + jc];
                v = (s != N) ? g : N;
            }
            gm[m][t] = v;
        }

    f32x16 acc = {};
    const char* fb = (const char*)featsh;
    const char* wb = (const char*)w1f;
    #pragma unroll
    for (int m = 0; m < 8; ++m) {
        short4v lo = *(const short4v*)(fb + (size_t)gm[m][0] * 8);
        short4v hi = *(const short4v*)(fb + (size_t)gm[m][1] * 8);
        short8v a = __builtin_shufflevector(lo, hi, 0, 1, 2, 3, 4, 5, 6, 7);
        short8v b = *(const short8v*)(wb + (m * 512 + r * 16 + h * 8) * 2);
        acc = __builtin_amdgcn_mfma_f32_32x32x16_bf16(a, b, acc, 0, 0, 0);
    }
    // C/D: col = lane&31, row = (reg&3) + 8*(reg>>2) + 4*h
    #pragma unroll
    for (int reg = 0; reg < 16; ++reg) {
        int row = (reg & 3) + 8 * (reg >> 2) + 4 * h;
        int j2 = rbase + row;
        if (j2 < N) x1h[(size_t)j2 * 32 + r] = f2bf(acc[reg]);
    }
}

// ---------------------------------------------------------------------------
// conv2: x1h [N+1,32] bf16 x w2h -> x2 [M,32] f32.
// 32x32x16 MFMA: 32 rows/wave, per-lane global gather, no LDS/sync.
// ---------------------------------------------------------------------------
__global__ __launch_bounds__(256) void conv2_k(
    const unsigned short* __restrict__ x1h, const unsigned short* __restrict__ w2h,
    const int* __restrict__ g2, const int* __restrict__ s2,
    float* __restrict__ x2, int M, int N)
{
    int tid = threadIdx.x;
    int l = tid & 63, wv = tid >> 6;
    int r = l & 31, h = l >> 5;
    int rbase = blockIdx.x * 128 + wv * 32;
    int j = rbase + r;
    int jc = j < M ? j : M - 1;

    int gm[27];
    #pragma unroll
    for (int k = 0; k < 27; ++k) {
        int s = s2[(size_t)k * M + jc];
        int g = g2[(size_t)k * M + jc];
        gm[k] = (j < M && s != M) ? g : N;      // row N of x1h is zeros
    }

    f32x16 acc = {};
    const char* xb = (const char*)x1h;
    const char* wb = (const char*)w2h;
    #pragma unroll
    for (int k = 0; k < 27; ++k) {
        const char* xr = xb + (size_t)gm[k] * 64;
        short8v a0 = *(const short8v*)(xr + h * 16);          // ch h*8..+8
        short8v a1 = *(const short8v*)(xr + 32 + h * 16);     // ch 16+h*8..+8
        short8v b0 = *(const short8v*)(wb + k * 2048 + r * 64 + h * 16);
        short8v b1 = *(const short8v*)(wb + k * 2048 + r * 64 + 32 + h * 16);
        acc = __builtin_amdgcn_mfma_f32_32x32x16_bf16(a0, b0, acc, 0, 0, 0);
        acc = __builtin_amdgcn_mfma_f32_32x32x16_bf16(a1, b1, acc, 0, 0, 0);
    }
    #pragma unroll
    for (int reg = 0; reg < 16; ++reg) {
        int row = (reg & 3) + 8 * (reg >> 2) + 4 * h;
        int j2 = rbase + row;
        if (j2 < M) x2[(size_t)j2 * 32 + r] = acc[reg];
    }
}

// ---------------------------------------------------------------------------
// conv3: x2 [M,32] f32 x W3 [27,32,2] -> out [M,2]. 4 threads/row (8 ch each),
// hoisted masked indices, shfl_xor reduce. W3 in LDS.
// ---------------------------------------------------------------------------
__global__ __launch_bounds__(256) void conv3_k(
    const float* __restrict__ x2, const float* __restrict__ W3,
    const int* __restrict__ g3, const int* __restrict__ s3,
    float* __restrict__ out, int M)
{
    __shared__ float w[27 * 64];
    int tid = threadIdx.x;
    for (int i = tid; i < 27 * 64; i += 256) w[i] = W3[i];
    __syncthreads();

    int q = tid & 3;
    int j = blockIdx.x * 64 + (tid >> 2);
    int jc = j < M ? j : M - 1;

    int gm[27];
    #pragma unroll
    for (int k = 0; k < 27; ++k) {
        int s = s3[(size_t)k * M + jc];
        int g = g3[(size_t)k * M + jc];
        gm[k] = (s != M) ? g : -1;
    }

    float a0 = 0.f, a1 = 0.f;
    #pragma unroll
    for (int k = 0; k < 27; ++k) {
        float m = gm[k] >= 0 ? 1.f : 0.f;
        int g = gm[k] >= 0 ? gm[k] : 0;
        const float* xr = x2 + (size_t)g * 32 + q * 8;
        float4 f0 = *(const float4*)(xr);
        float4 f1 = *(const float4*)(xr + 4);
        const float* wk = w + k * 64 + q * 16;
        float4 wA = *(const float4*)(wk);
        float4 wB = *(const float4*)(wk + 4);
        float4 wC = *(const float4*)(wk + 8);
        float4 wD = *(const float4*)(wk + 12);
        a0 += m * (f0.x * wA.x + f0.y * wA.z + f0.z * wB.x + f0.w * wB.z
                 + f1.x * wC.x + f1.y * wC.z + f1.z * wD.x + f1.w * wD.z);
        a1 += m * (f0.x * wA.y + f0.y * wA.w + f0.z * wB.y + f0.w * wB.w
                 + f1.x * wC.y + f1.y * wC.w + f1.z * wD.y + f1.w * wD.w);
    }
    a0 += __shfl_xor(a0, 1); a0 += __shfl_xor(a0, 2);
    a1 += __shfl_xor(a1, 1); a1 += __shfl_xor(a1, 2);
    if (q == 0 && j < M)
        *reinterpret_cast<float2*>(out + (size_t)j * 2) = make_float2(a0, a1);
}

// ---------------------------------------------------------------------------
extern "C" void kernel_launch(void* const* d_in, const int* in_sizes, int n_in,
                              void* d_out, int out_size, void* d_ws, size_t ws_size,
                              hipStream_t stream) {
    const float* feats = (const float*)d_in[0];
    const float* W1    = (const float*)d_in[1];
    const float* W2    = (const float*)d_in[2];
    const float* W3    = (const float*)d_in[3];
    const int*   g1    = (const int*)d_in[4];
    const int*   s1    = (const int*)d_in[5];
    const int*   g2    = (const int*)d_in[6];
    const int*   s2    = (const int*)d_in[7];
    const int*   g3    = (const int*)d_in[8];
    const int*   s3    = (const int*)d_in[9];

    int N = in_sizes[0] / 4;    // 200000
    int M = in_sizes[6] / 27;   // stride-2 output count

    char* wsb = (char*)d_ws;
    size_t off = 0;
    auto alloc = [&](size_t bytes) {
        char* p = wsb + off;
        off = (off + bytes + 255) & ~(size_t)255;
        return p;
    };
    unsigned short* x1h    = (unsigned short*)alloc((size_t)(N + 1) * 64); // [N+1,32] bf16
    unsigned short* featsh = (unsigned short*)alloc((size_t)(N + 1) * 8);  // [N+1,4]  bf16
    unsigned short* w2h    = (unsigned short*)alloc(27 * 1024 * 2);        // [27,32,32] bf16 (B^T)
    unsigned short* w1f    = (unsigned short*)alloc(8 * 512 * 2);          // [8,32,16]  bf16 (folded)
    float*          x2     = (float*)alloc((size_t)M * 128);               // [M,32] f32
    float* out = (float*)d_out;

    prep_feats_k<<<CDIV(N + 1, 256), 256, 0, stream>>>(feats, featsh, x1h, N);
    prep_w_k<<<CDIV(27 * 1024 + 4096, 256), 256, 0, stream>>>(W1, W2, w2h, w1f);
    conv1_k<<<CDIV(N, 128), 256, 0, stream>>>(featsh, w1f, g1, s1, x1h, N);
    conv2_k<<<CDIV(M, 128), 256, 0, stream>>>(x1h, w2h, g2, s2, x2, M, N);
    conv3_k<<<CDIV(M, 64),  256, 0, stream>>>(x2, W3, g3, s3, out, M);
}